// Round 1
// 354.397 us; speedup vs baseline: 1.0118x; 1.0118x over previous
//
#include <hip/hip_runtime.h>
#include <hip/hip_bf16.h>

// Attention forward, MI355X (gfx950). fp32 in/out, bf16 MFMA internally.
// ws (56 MB): wqkv_b[3072x1024 bf16] | wo_b[1024x1024 bf16] | QKV[8192x3072 bf16]
// xb (bf16 x) lives in d_out's first 16 MB (dead before out-proj writes).
// Dispatches: 5 converts; QKV GEMM (bf16 m97-style); flash (paired q-tiles,
// fixed-shift softmax, Z in-place over Q cols); out-proj GEMM (fp32 out).
// MFMA layouts (verified m89/m74):
//   A-frag: A[m=lane&15][k=(lane>>4)*8+j]; B-frag: B[n=lane&15][k=...]
//   C/D:    col=lane&15, row=(lane>>4)*4+reg
//
// Round-8 change: LDS swizzles fixed for BOTH read and write sides.
//   vt chunk swizzle: (p>>3)^(h>>3)  ->  (p>>3)^(h>>3)^(h&7).
//     Old: PV ds_read_b128 spanned only 4/8 chunk slots (hrow>>3 has 1 varying
//     bit, quad only 2) -> 16/32 banks -> 4x serialization, ~70% of the 1.6e7
//     SQ_LDS_BANK_CONFLICT cycles (16% of all CU-cycles). New XOR includes
//     lm&7 -> all 8 slots uniformly on reads; writes keep tid&7 spread. Free
//     both ways.
//   pbuf: PS 72->64 + 16B-chunk XOR by (lm&7); writes packed as uint2 (8->4
//     stores). Old even-bank layout was 4-way on writes. New: exact bank floor.

typedef short short8 __attribute__((ext_vector_type(8)));
typedef float f32x4 __attribute__((ext_vector_type(4)));

#define MFMA16(a, b, c) __builtin_amdgcn_mfma_f32_16x16x32_bf16((a), (b), (c), 0, 0, 0)

static __device__ __forceinline__ ushort f2bf(float f) {
  union { __hip_bfloat16 h; ushort u; } cv;
  cv.h = __float2bfloat16(f);
  return cv.u;
}

static __device__ __forceinline__ float fexp2(float x) {
#if __has_builtin(__builtin_amdgcn_exp2f)
  return __builtin_amdgcn_exp2f(x);
#else
  return __expf(x * 0.69314718056f);
#endif
}

static __device__ __forceinline__ void store_out(float* p, float v) { *p = v; }
static __device__ __forceinline__ void store_out(__hip_bfloat16* p, float v) {
  *p = __float2bfloat16(v);
}

__global__ __launch_bounds__(256) void f32_to_bf16_kernel(
    const float* __restrict__ in, ushort* __restrict__ out, int n4) {
  int i = blockIdx.x * blockDim.x + threadIdx.x;
  if (i >= n4) return;
  const float4 v = ((const float4*)in)[i];
  ushort4 o;
  o.x = f2bf(v.x); o.y = f2bf(v.y); o.z = f2bf(v.z); o.w = f2bf(v.w);
  ((ushort4*)out)[i] = o;
}

// C[M,N] = A[M,K](bf16) * B[N,K]^T(bf16), fp32 acc. m97 structure: 128x128
// block tile, BK=32, both operands staged via global_load_lds width 16,
// ds_read_b128 fragments. Block 256 = 4 waves, wave tile 64x64.
template <typename OUT_T>
__global__ __launch_bounds__(256) void gemm_kernel(
    const ushort* __restrict__ A, int lda, const ushort* __restrict__ B, int ldb,
    OUT_T* __restrict__ C, int ldc, int K) {
  __shared__ __align__(16) ushort As[128 * 32];
  __shared__ __align__(16) ushort Bs[128 * 32];
  const int tid = threadIdx.x;
  const int wave = tid >> 6, lane = tid & 63;
  const int lm = lane & 15, quad = lane >> 4;
  const size_t m0 = (size_t)blockIdx.y * 128;
  const size_t n0 = (size_t)blockIdx.x * 128;
  const int srow = lane >> 2;       // 4 lanes/row * 8 ushort
  const int scol = (lane & 3) * 8;

  f32x4 acc[4][4] = {};
  for (int k0 = 0; k0 < K; k0 += 32) {
    __syncthreads();
#pragma unroll
    for (int j = 0; j < 2; ++j) {
      const int ch = wave * 2 + j;  // 16-row chunk
      const ushort* gb = B + (n0 + ch * 16 + srow) * (size_t)ldb + k0 + scol;
      __builtin_amdgcn_global_load_lds(
          (const __attribute__((address_space(1))) void*)gb,
          (__attribute__((address_space(3))) void*)(Bs + ch * 512), 16, 0, 0);
      const ushort* ga = A + (m0 + ch * 16 + srow) * (size_t)lda + k0 + scol;
      __builtin_amdgcn_global_load_lds(
          (const __attribute__((address_space(1))) void*)ga,
          (__attribute__((address_space(3))) void*)(As + ch * 512), 16, 0, 0);
    }
    __syncthreads();

    const int wm = (wave >> 1) * 64, wn = (wave & 1) * 64;
    short8 a[4], b[4];
#pragma unroll
    for (int i = 0; i < 4; ++i)
      a[i] = *(const short8*)(As + (wm + i * 16 + lm) * 32 + quad * 8);
#pragma unroll
    for (int j = 0; j < 4; ++j)
      b[j] = *(const short8*)(Bs + (wn + j * 16 + lm) * 32 + quad * 8);
#pragma unroll
    for (int i = 0; i < 4; ++i)
#pragma unroll
      for (int j = 0; j < 4; ++j)
        acc[i][j] = MFMA16(a[i], b[j], acc[i][j]);
  }

  const int wm = (wave >> 1) * 64, wn = (wave & 1) * 64;
  const int rq = quad * 4;
#pragma unroll
  for (int i = 0; i < 4; ++i)
#pragma unroll
    for (int j = 0; j < 4; ++j)
#pragma unroll
      for (int r = 0; r < 4; ++r)
        store_out(&C[(m0 + wm + i * 16 + rq + r) * (size_t)ldc + n0 + wn + j * 16 + lm],
                  acc[i][j][r]);
}

// Swizzled V^T LDS write: 8 cols starting at h0 for row p.
// Element (p, h) lives at h*64 + (((p>>3) ^ (h>>3) ^ (h&7)) & 7)*8 + (p&7).
// Here h = h0+u with h0 = hsw*8, so h>>3 = hsw, h&7 = u.
// Per store-u instruction, (p>>3) is wave-constant and hsw spans 0..7 across
// lanes -> all 32 banks covered, 2 adjacent-ushort lanes/bank (free).
static __device__ __forceinline__ void vt_write8(ushort* vtbuf, int h0, int hsw,
                                                 int p, const short8& v) {
  const int pc = (p >> 3) ^ hsw;
  ushort* row = vtbuf + h0 * 64 + (p & 7);
#pragma unroll
  for (int u = 0; u < 8; ++u)
    row[u * 64 + (((pc ^ u) & 7) << 3)] = ((const ushort*)&v)[u];
}

// Flash causal attention. QKV[8192][3072]: Q cols 0..1023, K 1024..2047,
// V 2048..3071; head h at sub-col h*64; row = b*2048 + pos. Z over Q in-place.
// Grid (16,16,4): block handles q-tile pair (bx, 31-bx) -> exactly 33 p-tile
// iters per block (balance by construction, immune to dispatch mapping;
// round-7 lesson: 32|256 makes same-CU blocks share qbi, LPT fails).
// Block = 4 waves; wave = 16 q-rows. S^T = K*Q^T: lane owns q-row qrow+lm.
// Fixed-shift softmax: p = exp2(S*log2e/8) (exact; scores bounded ~10),
// l accumulated per-lane, reduced once in epilogue. K prefetched to regs;
// V^T double-buffered in LDS (xor-swizzled both-sides); P via per-wave LDS
// (no barrier), 16B-chunk xor-swizzled by row (lm&7), row stride 64 (no pad).
__global__ __launch_bounds__(256) void flash4_kernel(ushort* __restrict__ QKV) {
  constexpr int LD = 3072;
  __shared__ __align__(16) ushort vt[2][64 * 64];
  __shared__ __align__(16) ushort pbuf[4][16 * 64];

  const int head = blockIdx.y;
  const int b = blockIdx.z;
  const int tid = threadIdx.x;
  const int wave = tid >> 6, lane = tid & 63;
  const int lm = lane & 15, quad = lane >> 4;

  const size_t qcol = (size_t)b * 2048 * LD + head * 64;
  const size_t kcol = qcol + 1024;
  const size_t vcol = qcol + 2048;

  const int h0 = (tid & 7) * 8;  // staging: 8 V-cols per thread
  const int hsw = tid & 7;       // == h>>3 for those cols
  const int plb = tid >> 3;      // staging p base (0..31)
  const int psw = lm & 7;        // pbuf row swizzle key

  constexpr float CSC = 0.180336880f;  // log2(e)/8

  for (int pass = 0; pass < 2; ++pass) {
    const int qbi = pass ? 31 - (int)blockIdx.x : (int)blockIdx.x;
    const int qb = qbi * 64;
    const int qrow = qb + wave * 16;
    const int qg = qrow + lm;
    const int nt = qbi + 1;

    const ushort* qp = QKV + qcol + (size_t)(qrow + lm) * LD;
    short8 qa0 = *(const short8*)(qp + quad * 8);
    short8 qa1 = *(const short8*)(qp + 32 + quad * 8);

    f32x4 accz[4] = {};   // Z C-layout: row q=quad*4+r, col h=c*16+lm
    float l_l = 0.f;      // per-lane partial row-sum for row qg

    // K fragments for tile 0 (registers)
    short8 ka[4], kb[4];
#pragma unroll
    for (int s = 0; s < 4; ++s) {
      const ushort* kp = QKV + kcol + (size_t)(s * 16 + lm) * LD;
      ka[s] = *(const short8*)(kp + quad * 8);
      kb[s] = *(const short8*)(kp + 32 + quad * 8);
    }

    __syncthreads();  // prior pass's vt reads complete before restage
    // V tile 0 -> vt[0]
#pragma unroll
    for (int rr = 0; rr < 2; ++rr) {
      const int p = plb + rr * 32;
      short8 v = *(const short8*)(QKV + vcol + (size_t)p * LD + h0);
      vt_write8(vt[0], h0, hsw, p, v);
    }

    for (int it = 0; it < nt; ++it) {
      const int p0 = it * 64;
      __syncthreads();  // vt[it&1] visible; prior reads of other buf done

      // early global V load for it+1 (LDS write deferred to end of iter)
      short8 nv0, nv1;
      const bool more = (it + 1 < nt);
      if (more) {
        nv0 = *(const short8*)(QKV + vcol + (size_t)(p0 + 64 + plb) * LD + h0);
        nv1 = *(const short8*)(QKV + vcol + (size_t)(p0 + 96 + plb) * LD + h0);
      }

      // scores S^T[p][q] (8 MFMA), consuming prefetched K
      f32x4 t4[4];
#pragma unroll
      for (int s = 0; s < 4; ++s) {
        f32x4 t = {0.f, 0.f, 0.f, 0.f};
        t = MFMA16(ka[s], qa0, t);
        t = MFMA16(kb[s], qa1, t);
        t4[s] = t;
      }
      // reload K for it+1 (loads fly during this iter's tail)
      if (more) {
#pragma unroll
        for (int s = 0; s < 4; ++s) {
          const ushort* kp = QKV + kcol + (size_t)(p0 + 64 + s * 16 + lm) * LD;
          ka[s] = *(const short8*)(kp + quad * 8);
          kb[s] = *(const short8*)(kp + 32 + quad * 8);
        }
      }

      // fixed-shift softmax: p = exp2(S*log2e/8); mask only on diagonal tile
      float ps[4][4];
      if (it != nt - 1) {
#pragma unroll
        for (int s = 0; s < 4; ++s) {
#pragma unroll
          for (int r = 0; r < 4; ++r)
            ps[s][r] = fexp2(t4[s][r] * CSC);
          l_l += (ps[s][0] + ps[s][1]) + (ps[s][2] + ps[s][3]);
        }
      } else {
#pragma unroll
        for (int s = 0; s < 4; ++s) {
#pragma unroll
          for (int r = 0; r < 4; ++r) {
            const int pg = p0 + s * 16 + quad * 4 + r;
            const float e = fexp2(t4[s][r] * CSC);
            ps[s][r] = (pg > qg) ? 0.f : e;
          }
          l_l += (ps[s][0] + ps[s][1]) + (ps[s][2] + ps[s][3]);
        }
      }

      // pack P^T (C-layout) -> per-wave LDS (same-wave, no barrier).
      // Row q=lm, 64 ushorts, 16B chunks xor'd by psw. Lane (lm,quad) owns
      // ushorts s*16+quad*4+{0..3} -> chunk 2s+(quad>>1), sub (quad&1)*4.
      // One uint2 per s: 4 stores/iter, exact bank floor (4 lanes/bank,
      // 512B/instr = 4-clock minimum).
      ushort* pw = pbuf[wave] + lm * 64;
#pragma unroll
      for (int s = 0; s < 4; ++s) {
        uint2 pk;
        pk.x = (uint)f2bf(ps[s][0]) | ((uint)f2bf(ps[s][1]) << 16);
        pk.y = (uint)f2bf(ps[s][2]) | ((uint)f2bf(ps[s][3]) << 16);
        *(uint2*)(pw + ((((2 * s + (quad >> 1)) ^ psw) & 7) << 3) +
                  ((quad & 1) << 2)) = pk;
      }

      // PV: accz[q][h] += P[q][p] * V[p][h]
      const ushort* vbuf = vt[it & 1];
#pragma unroll
      for (int kc = 0; kc < 2; ++kc) {
        // P^T row lm, chunk kc*4+quad (8 consecutive p), xor'd by psw
        short8 pa = *(const short8*)(pw + ((((kc * 4 + quad) ^ psw) & 7) << 3));
#pragma unroll
        for (int c = 0; c < 4; ++c) {
          const int hrow = c * 16 + lm;
          const int fh = ((hrow >> 3) ^ hrow) & 7;  // read-side swizzle key
          short8 vb = *(const short8*)(
              vbuf + hrow * 64 + ((((4 * kc + quad) ^ fh) & 7) << 3));
          accz[c] = MFMA16(pa, vb, accz[c]);
        }
      }

      // late LDS writes of next V tile (other buffer)
      if (more) {
        ushort* nbuf = vt[(it + 1) & 1];
        vt_write8(nbuf, h0, hsw, plb, nv0);
        vt_write8(nbuf, h0, hsw, plb + 32, nv1);
      }
    }

    // epilogue: full row-sums via 2 shfl_xor, then scale + write Z over Q
    float lt = l_l;
    lt += __shfl_xor(lt, 16, 64);
    lt += __shfl_xor(lt, 32, 64);
#pragma unroll
    for (int r = 0; r < 4; ++r) {
      const float lr = __shfl(lt, quad * 4 + r, 64);
      const float inv = 1.f / lr;
#pragma unroll
      for (int c = 0; c < 4; ++c)
        QKV[qcol + (size_t)(qrow + quad * 4 + r) * LD + c * 16 + lm] =
            f2bf(accz[c][r] * inv);
    }
  }
}

extern "C" void kernel_launch(void* const* d_in, const int* in_sizes, int n_in,
                              void* d_out, int out_size, void* d_ws, size_t ws_size,
                              hipStream_t stream) {
  (void)in_sizes; (void)n_in; (void)out_size; (void)ws_size;
  const float* x  = (const float*)d_in[0];   // (4,2048,1024) = (8192,1024)
  const float* wk = (const float*)d_in[1];   // (16,64,1024) flat (1024,1024)
  const float* wq = (const float*)d_in[2];
  const float* wv = (const float*)d_in[3];
  const float* wo = (const float*)d_in[4];   // (1024,1024)
  float* out = (float*)d_out;

  const size_t WSZ = (size_t)1024 * 1024;
  ushort* wqkv_b = (ushort*)d_ws;            // rows: 0..1023 Q, 1024.. K, 2048.. V
  ushort* wo_b = wqkv_b + 3 * WSZ;
  ushort* QKV = wo_b + WSZ;                  // 8192 x 3072
  ushort* xb = (ushort*)d_out;               // bf16 x in d_out (16 of 32 MB);
                                             // dead before out-proj writes

  const int wn4 = (int)(WSZ / 4);
  const int xn4 = (int)((size_t)8192 * 1024 / 4);
  f32_to_bf16_kernel<<<(wn4 + 255) / 256, 256, 0, stream>>>(wq, wqkv_b, wn4);
  f32_to_bf16_kernel<<<(wn4 + 255) / 256, 256, 0, stream>>>(wk, wqkv_b + WSZ, wn4);
  f32_to_bf16_kernel<<<(wn4 + 255) / 256, 256, 0, stream>>>(wv, wqkv_b + 2 * WSZ, wn4);
  f32_to_bf16_kernel<<<(wn4 + 255) / 256, 256, 0, stream>>>(wo, wo_b, wn4);
  f32_to_bf16_kernel<<<(xn4 + 255) / 256, 256, 0, stream>>>(x, xb, xn4);

  // All-batch QKV projection (pure bf16, global_load_lds staging).
  gemm_kernel<__hip_bfloat16><<<dim3(24, 64), 256, 0, stream>>>(
      xb, 1024, wqkv_b, 1024, (__hip_bfloat16*)QKV, 3072, 1024);

  flash4_kernel<<<dim3(16, 16, 4), 256, 0, stream>>>(QKV);

  // Out projection: Z (QKV cols 0..1023) * Wo^T -> fp32 out.
  gemm_kernel<float><<<dim3(8, 64), 256, 0, stream>>>(
      QKV, 3072, wo_b, 1024, out, 1024, 1024);
}

// Round 2
// 346.030 us; speedup vs baseline: 1.0363x; 1.0242x over previous
//
#include <hip/hip_runtime.h>
#include <hip/hip_bf16.h>

// Attention forward, MI355X (gfx950). fp32 in/out, bf16 MFMA internally.
// ws (56 MB): wqkv_b[3072x1024 bf16] | wo_b[1024x1024 bf16] | QKV[8192x3072 bf16]
// xb (bf16 x) lives in d_out's first 16 MB (dead before out-proj writes).
// Dispatches: 5 converts; QKV GEMM (bf16 m97-style); flash (paired q-tiles,
// fixed-shift softmax, Z in-place over Q cols); out-proj GEMM (fp32 out).
// MFMA layouts (verified m89/m74):
//   A-frag: A[m=lane&15][k=(lane>>4)*8+j]; B-frag: B[n=lane&15][k=...]
//   C/D:    col=lane&15, row=(lane>>4)*4+reg
//
// Round-8: both-sides LDS swizzles (vt chunk ^= h&7; pbuf 16B-chunk ^= lm&7).
//   Result: SQ_LDS_BANK_CONFLICT 1.62e7 -> 6.5e6, dur unchanged -> DS pipe
//   was not pacing. Kept (free).
// Round-9: replace per-iter __syncthreads with lgkmcnt(0)+raw s_barrier.
//   Theory: __syncthreads emits s_waitcnt vmcnt(0) before s_barrier, draining
//   the K/V prefetch queue every iteration (m97 barrier-drain stall). The raw
//   barrier keeps cross-wave LDS visibility (only vt needs it; pbuf is
//   per-wave, vt is double-buffered so one barrier/iter suffices) while
//   letting global loads fly across the barrier; consumers keep precise
//   compiler-inserted vmcnt(N) waits.

typedef short short8 __attribute__((ext_vector_type(8)));
typedef float f32x4 __attribute__((ext_vector_type(4)));

#define MFMA16(a, b, c) __builtin_amdgcn_mfma_f32_16x16x32_bf16((a), (b), (c), 0, 0, 0)

static __device__ __forceinline__ ushort f2bf(float f) {
  union { __hip_bfloat16 h; ushort u; } cv;
  cv.h = __float2bfloat16(f);
  return cv.u;
}

static __device__ __forceinline__ float fexp2(float x) {
#if __has_builtin(__builtin_amdgcn_exp2f)
  return __builtin_amdgcn_exp2f(x);
#else
  return __expf(x * 0.69314718056f);
#endif
}

// Barrier WITHOUT the __syncthreads vmcnt(0) drain: LDS writes made visible
// (lgkmcnt(0)), global loads stay in flight. asm memory clobber fences the
// compiler above; sched_barrier(0) pins subsequent LDS reads below.
static __device__ __forceinline__ void block_sync_lds() {
  asm volatile("s_waitcnt lgkmcnt(0)" ::: "memory");
  __builtin_amdgcn_s_barrier();
  __builtin_amdgcn_sched_barrier(0);
}

static __device__ __forceinline__ void store_out(float* p, float v) { *p = v; }
static __device__ __forceinline__ void store_out(__hip_bfloat16* p, float v) {
  *p = __float2bfloat16(v);
}

__global__ __launch_bounds__(256) void f32_to_bf16_kernel(
    const float* __restrict__ in, ushort* __restrict__ out, int n4) {
  int i = blockIdx.x * blockDim.x + threadIdx.x;
  if (i >= n4) return;
  const float4 v = ((const float4*)in)[i];
  ushort4 o;
  o.x = f2bf(v.x); o.y = f2bf(v.y); o.z = f2bf(v.z); o.w = f2bf(v.w);
  ((ushort4*)out)[i] = o;
}

// C[M,N] = A[M,K](bf16) * B[N,K]^T(bf16), fp32 acc. m97 structure: 128x128
// block tile, BK=32, both operands staged via global_load_lds width 16,
// ds_read_b128 fragments. Block 256 = 4 waves, wave tile 64x64.
template <typename OUT_T>
__global__ __launch_bounds__(256) void gemm_kernel(
    const ushort* __restrict__ A, int lda, const ushort* __restrict__ B, int ldb,
    OUT_T* __restrict__ C, int ldc, int K) {
  __shared__ __align__(16) ushort As[128 * 32];
  __shared__ __align__(16) ushort Bs[128 * 32];
  const int tid = threadIdx.x;
  const int wave = tid >> 6, lane = tid & 63;
  const int lm = lane & 15, quad = lane >> 4;
  const size_t m0 = (size_t)blockIdx.y * 128;
  const size_t n0 = (size_t)blockIdx.x * 128;
  const int srow = lane >> 2;       // 4 lanes/row * 8 ushort
  const int scol = (lane & 3) * 8;

  f32x4 acc[4][4] = {};
  for (int k0 = 0; k0 < K; k0 += 32) {
    __syncthreads();
#pragma unroll
    for (int j = 0; j < 2; ++j) {
      const int ch = wave * 2 + j;  // 16-row chunk
      const ushort* gb = B + (n0 + ch * 16 + srow) * (size_t)ldb + k0 + scol;
      __builtin_amdgcn_global_load_lds(
          (const __attribute__((address_space(1))) void*)gb,
          (__attribute__((address_space(3))) void*)(Bs + ch * 512), 16, 0, 0);
      const ushort* ga = A + (m0 + ch * 16 + srow) * (size_t)lda + k0 + scol;
      __builtin_amdgcn_global_load_lds(
          (const __attribute__((address_space(1))) void*)ga,
          (__attribute__((address_space(3))) void*)(As + ch * 512), 16, 0, 0);
    }
    __syncthreads();

    const int wm = (wave >> 1) * 64, wn = (wave & 1) * 64;
    short8 a[4], b[4];
#pragma unroll
    for (int i = 0; i < 4; ++i)
      a[i] = *(const short8*)(As + (wm + i * 16 + lm) * 32 + quad * 8);
#pragma unroll
    for (int j = 0; j < 4; ++j)
      b[j] = *(const short8*)(Bs + (wn + j * 16 + lm) * 32 + quad * 8);
#pragma unroll
    for (int i = 0; i < 4; ++i)
#pragma unroll
      for (int j = 0; j < 4; ++j)
        acc[i][j] = MFMA16(a[i], b[j], acc[i][j]);
  }

  const int wm = (wave >> 1) * 64, wn = (wave & 1) * 64;
  const int rq = quad * 4;
#pragma unroll
  for (int i = 0; i < 4; ++i)
#pragma unroll
    for (int j = 0; j < 4; ++j)
#pragma unroll
      for (int r = 0; r < 4; ++r)
        store_out(&C[(m0 + wm + i * 16 + rq + r) * (size_t)ldc + n0 + wn + j * 16 + lm],
                  acc[i][j][r]);
}

// Swizzled V^T LDS write: 8 cols starting at h0 for row p.
// Element (p, h) lives at h*64 + (((p>>3) ^ (h>>3) ^ (h&7)) & 7)*8 + (p&7).
// Here h = h0+u with h0 = hsw*8, so h>>3 = hsw, h&7 = u.
// Per store-u instruction, (p>>3) is wave-constant and hsw spans 0..7 across
// lanes -> all 32 banks covered, 2 adjacent-ushort lanes/bank (free).
static __device__ __forceinline__ void vt_write8(ushort* vtbuf, int h0, int hsw,
                                                 int p, const short8& v) {
  const int pc = (p >> 3) ^ hsw;
  ushort* row = vtbuf + h0 * 64 + (p & 7);
#pragma unroll
  for (int u = 0; u < 8; ++u)
    row[u * 64 + (((pc ^ u) & 7) << 3)] = ((const ushort*)&v)[u];
}

// Flash causal attention. QKV[8192][3072]: Q cols 0..1023, K 1024..2047,
// V 2048..3071; head h at sub-col h*64; row = b*2048 + pos. Z over Q in-place.
// Grid (16,16,4): block handles q-tile pair (bx, 31-bx) -> exactly 33 p-tile
// iters per block (balance by construction, immune to dispatch mapping;
// round-7 lesson: 32|256 makes same-CU blocks share qbi, LPT fails).
// Block = 4 waves; wave = 16 q-rows. S^T = K*Q^T: lane owns q-row qrow+lm.
// Fixed-shift softmax: p = exp2(S*log2e/8) (exact; scores bounded ~10),
// l accumulated per-lane, reduced once in epilogue. K prefetched to regs;
// V^T double-buffered in LDS (xor-swizzled both-sides); P via per-wave LDS
// (no barrier), 16B-chunk xor-swizzled by row (lm&7), row stride 64 (no pad).
__global__ __launch_bounds__(256) void flash4_kernel(ushort* __restrict__ QKV) {
  constexpr int LD = 3072;
  __shared__ __align__(16) ushort vt[2][64 * 64];
  __shared__ __align__(16) ushort pbuf[4][16 * 64];

  const int head = blockIdx.y;
  const int b = blockIdx.z;
  const int tid = threadIdx.x;
  const int wave = tid >> 6, lane = tid & 63;
  const int lm = lane & 15, quad = lane >> 4;

  const size_t qcol = (size_t)b * 2048 * LD + head * 64;
  const size_t kcol = qcol + 1024;
  const size_t vcol = qcol + 2048;

  const int h0 = (tid & 7) * 8;  // staging: 8 V-cols per thread
  const int hsw = tid & 7;       // == h>>3 for those cols
  const int plb = tid >> 3;      // staging p base (0..31)
  const int psw = lm & 7;        // pbuf row swizzle key

  constexpr float CSC = 0.180336880f;  // log2(e)/8

  for (int pass = 0; pass < 2; ++pass) {
    const int qbi = pass ? 31 - (int)blockIdx.x : (int)blockIdx.x;
    const int qb = qbi * 64;
    const int qrow = qb + wave * 16;
    const int qg = qrow + lm;
    const int nt = qbi + 1;

    const ushort* qp = QKV + qcol + (size_t)(qrow + lm) * LD;
    short8 qa0 = *(const short8*)(qp + quad * 8);
    short8 qa1 = *(const short8*)(qp + 32 + quad * 8);

    f32x4 accz[4] = {};   // Z C-layout: row q=quad*4+r, col h=c*16+lm
    float l_l = 0.f;      // per-lane partial row-sum for row qg

    // K fragments for tile 0 (registers)
    short8 ka[4], kb[4];
#pragma unroll
    for (int s = 0; s < 4; ++s) {
      const ushort* kp = QKV + kcol + (size_t)(s * 16 + lm) * LD;
      ka[s] = *(const short8*)(kp + quad * 8);
      kb[s] = *(const short8*)(kp + 32 + quad * 8);
    }

    block_sync_lds();  // prior pass's vt reads complete before restage
    // V tile 0 -> vt[0]
#pragma unroll
    for (int rr = 0; rr < 2; ++rr) {
      const int p = plb + rr * 32;
      short8 v = *(const short8*)(QKV + vcol + (size_t)p * LD + h0);
      vt_write8(vt[0], h0, hsw, p, v);
    }

    for (int it = 0; it < nt; ++it) {
      const int p0 = it * 64;
      // vt[it&1] visible; prior reads of other buf done. No vmcnt drain:
      // K loads issued last iter stay in flight across this barrier.
      block_sync_lds();

      // early global V load for it+1 (LDS write deferred to end of iter)
      short8 nv0, nv1;
      const bool more = (it + 1 < nt);
      if (more) {
        nv0 = *(const short8*)(QKV + vcol + (size_t)(p0 + 64 + plb) * LD + h0);
        nv1 = *(const short8*)(QKV + vcol + (size_t)(p0 + 96 + plb) * LD + h0);
      }

      // scores S^T[p][q] (8 MFMA), consuming prefetched K
      f32x4 t4[4];
#pragma unroll
      for (int s = 0; s < 4; ++s) {
        f32x4 t = {0.f, 0.f, 0.f, 0.f};
        t = MFMA16(ka[s], qa0, t);
        t = MFMA16(kb[s], qa1, t);
        t4[s] = t;
      }
      // reload K for it+1 (loads fly through this iter's tail AND across the
      // next barrier; consumer waits are compiler-counted vmcnt)
      if (more) {
#pragma unroll
        for (int s = 0; s < 4; ++s) {
          const ushort* kp = QKV + kcol + (size_t)(p0 + 64 + s * 16 + lm) * LD;
          ka[s] = *(const short8*)(kp + quad * 8);
          kb[s] = *(const short8*)(kp + 32 + quad * 8);
        }
      }

      // fixed-shift softmax: p = exp2(S*log2e/8); mask only on diagonal tile
      float ps[4][4];
      if (it != nt - 1) {
#pragma unroll
        for (int s = 0; s < 4; ++s) {
#pragma unroll
          for (int r = 0; r < 4; ++r)
            ps[s][r] = fexp2(t4[s][r] * CSC);
          l_l += (ps[s][0] + ps[s][1]) + (ps[s][2] + ps[s][3]);
        }
      } else {
#pragma unroll
        for (int s = 0; s < 4; ++s) {
#pragma unroll
          for (int r = 0; r < 4; ++r) {
            const int pg = p0 + s * 16 + quad * 4 + r;
            const float e = fexp2(t4[s][r] * CSC);
            ps[s][r] = (pg > qg) ? 0.f : e;
          }
          l_l += (ps[s][0] + ps[s][1]) + (ps[s][2] + ps[s][3]);
        }
      }

      // pack P^T (C-layout) -> per-wave LDS (same-wave, no barrier).
      // Row q=lm, 64 ushorts, 16B chunks xor'd by psw. Lane (lm,quad) owns
      // ushorts s*16+quad*4+{0..3} -> chunk 2s+(quad>>1), sub (quad&1)*4.
      // One uint2 per s: 4 stores/iter, exact bank floor.
      ushort* pw = pbuf[wave] + lm * 64;
#pragma unroll
      for (int s = 0; s < 4; ++s) {
        uint2 pk;
        pk.x = (uint)f2bf(ps[s][0]) | ((uint)f2bf(ps[s][1]) << 16);
        pk.y = (uint)f2bf(ps[s][2]) | ((uint)f2bf(ps[s][3]) << 16);
        *(uint2*)(pw + ((((2 * s + (quad >> 1)) ^ psw) & 7) << 3) +
                  ((quad & 1) << 2)) = pk;
      }

      // PV: accz[q][h] += P[q][p] * V[p][h]
      const ushort* vbuf = vt[it & 1];
#pragma unroll
      for (int kc = 0; kc < 2; ++kc) {
        // P^T row lm, chunk kc*4+quad (8 consecutive p), xor'd by psw
        short8 pa = *(const short8*)(pw + ((((kc * 4 + quad) ^ psw) & 7) << 3));
#pragma unroll
        for (int c = 0; c < 4; ++c) {
          const int hrow = c * 16 + lm;
          const int fh = ((hrow >> 3) ^ hrow) & 7;  // read-side swizzle key
          short8 vb = *(const short8*)(
              vbuf + hrow * 64 + ((((4 * kc + quad) ^ fh) & 7) << 3));
          accz[c] = MFMA16(pa, vb, accz[c]);
        }
      }

      // late LDS writes of next V tile (other buffer); compiler inserts the
      // precise vmcnt wait for nv0/nv1 here (issued a full iter ago).
      if (more) {
        ushort* nbuf = vt[(it + 1) & 1];
        vt_write8(nbuf, h0, hsw, plb, nv0);
        vt_write8(nbuf, h0, hsw, plb + 32, nv1);
      }
    }

    // epilogue: full row-sums via 2 shfl_xor, then scale + write Z over Q
    float lt = l_l;
    lt += __shfl_xor(lt, 16, 64);
    lt += __shfl_xor(lt, 32, 64);
#pragma unroll
    for (int r = 0; r < 4; ++r) {
      const float lr = __shfl(lt, quad * 4 + r, 64);
      const float inv = 1.f / lr;
#pragma unroll
      for (int c = 0; c < 4; ++c)
        QKV[qcol + (size_t)(qrow + quad * 4 + r) * LD + c * 16 + lm] =
            f2bf(accz[c][r] * inv);
    }
  }
}

extern "C" void kernel_launch(void* const* d_in, const int* in_sizes, int n_in,
                              void* d_out, int out_size, void* d_ws, size_t ws_size,
                              hipStream_t stream) {
  (void)in_sizes; (void)n_in; (void)out_size; (void)ws_size;
  const float* x  = (const float*)d_in[0];   // (4,2048,1024) = (8192,1024)
  const float* wk = (const float*)d_in[1];   // (16,64,1024) flat (1024,1024)
  const float* wq = (const float*)d_in[2];
  const float* wv = (const float*)d_in[3];
  const float* wo = (const float*)d_in[4];   // (1024,1024)
  float* out = (float*)d_out;

  const size_t WSZ = (size_t)1024 * 1024;
  ushort* wqkv_b = (ushort*)d_ws;            // rows: 0..1023 Q, 1024.. K, 2048.. V
  ushort* wo_b = wqkv_b + 3 * WSZ;
  ushort* QKV = wo_b + WSZ;                  // 8192 x 3072
  ushort* xb = (ushort*)d_out;               // bf16 x in d_out (16 of 32 MB);
                                             // dead before out-proj writes

  const int wn4 = (int)(WSZ / 4);
  const int xn4 = (int)((size_t)8192 * 1024 / 4);
  f32_to_bf16_kernel<<<(wn4 + 255) / 256, 256, 0, stream>>>(wq, wqkv_b, wn4);
  f32_to_bf16_kernel<<<(wn4 + 255) / 256, 256, 0, stream>>>(wk, wqkv_b + WSZ, wn4);
  f32_to_bf16_kernel<<<(wn4 + 255) / 256, 256, 0, stream>>>(wv, wqkv_b + 2 * WSZ, wn4);
  f32_to_bf16_kernel<<<(wn4 + 255) / 256, 256, 0, stream>>>(wo, wo_b, wn4);
  f32_to_bf16_kernel<<<(xn4 + 255) / 256, 256, 0, stream>>>(x, xb, xn4);

  // All-batch QKV projection (pure bf16, global_load_lds staging).
  gemm_kernel<__hip_bfloat16><<<dim3(24, 64), 256, 0, stream>>>(
      xb, 1024, wqkv_b, 1024, (__hip_bfloat16*)QKV, 3072, 1024);

  flash4_kernel<<<dim3(16, 16, 4), 256, 0, stream>>>(QKV);

  // Out projection: Z (QKV cols 0..1023) * Wo^T -> fp32 out.
  gemm_kernel<float><<<dim3(8, 64), 256, 0, stream>>>(
      QKV, 3072, wo_b, 1024, out, 1024, 1024);
}

// Round 3
// 280.803 us; speedup vs baseline: 1.2770x; 1.2323x over previous
//
#include <hip/hip_runtime.h>
#include <hip/hip_bf16.h>

// Attention forward, MI355X (gfx950). fp32 in/out, bf16 MFMA internally.
// ws (56 MB): wqkv_b[3072x1024 bf16] | wo_b[1024x1024 bf16] | QKV[8192x3072 bf16]
// xb (bf16 x) lives in d_out's first 16 MB (dead before out-proj writes).
// Dispatches: 5 converts; QKV GEMM (bf16 m97-style); flash (paired q-tiles,
// fixed-shift softmax, Z in-place over Q cols); out-proj GEMM (fp32 out).
// MFMA layouts (verified m89/m74):
//   A-frag: A[m=lane&15][k=(lane>>4)*8+j]; B-frag: B[n=lane&15][k=...]
//   C/D:    col=lane&15, row=(lane>>4)*4+reg
//
// Round-8: both-sides LDS swizzles. Bank conflicts 1.62e7->6.5e6, dur flat.
// Round-9: lgkm-only barrier (no vmcnt drain). 163->157 us. Drain was minor.
// Round-10 (this): counters said every pipe idle at ~11.4K cyc/iter ->
//   latency-bound on the K/V global stream. FETCH_SIZE 240MB vs 48MB data =
//   per-XCD L2 refetch (16 blocks of a (b,head) sprayed over 8 XCDs) plus
//   4x per-wave K reload redundancy. Fixes:
//   (a) K staged in LDS per block via global_load_lds (double-buffered kt[2]),
//       pre-swizzled SOURCE + swizzled ds_read (m173/rule-21 pattern).
//   (b) XCD-aware flat-grid remap: all 16 q-blocks of one (b,head) on one XCD
//       (id&7 = xcd, 8 groups/XCD, bijective).
//   LDS 40960 B/block -> still exactly 4 blocks/CU.

typedef short short8 __attribute__((ext_vector_type(8)));
typedef float f32x4 __attribute__((ext_vector_type(4)));

#define MFMA16(a, b, c) __builtin_amdgcn_mfma_f32_16x16x32_bf16((a), (b), (c), 0, 0, 0)

static __device__ __forceinline__ ushort f2bf(float f) {
  union { __hip_bfloat16 h; ushort u; } cv;
  cv.h = __float2bfloat16(f);
  return cv.u;
}

static __device__ __forceinline__ float fexp2(float x) {
#if __has_builtin(__builtin_amdgcn_exp2f)
  return __builtin_amdgcn_exp2f(x);
#else
  return __expf(x * 0.69314718056f);
#endif
}

// Barrier WITHOUT any vmcnt drain: LDS writes visible, globals keep flying.
static __device__ __forceinline__ void block_sync_lds() {
  asm volatile("s_waitcnt lgkmcnt(0)" ::: "memory");
  __builtin_amdgcn_s_barrier();
  __builtin_amdgcn_sched_barrier(0);
}

// Barrier that ALSO waits outstanding globals (needed when global_load_lds
// staging must be visible to other waves). Only 2 well-aged stage loads are
// in flight when this runs.
static __device__ __forceinline__ void block_sync_full() {
  asm volatile("s_waitcnt vmcnt(0) lgkmcnt(0)" ::: "memory");
  __builtin_amdgcn_s_barrier();
  __builtin_amdgcn_sched_barrier(0);
}

static __device__ __forceinline__ void store_out(float* p, float v) { *p = v; }
static __device__ __forceinline__ void store_out(__hip_bfloat16* p, float v) {
  *p = __float2bfloat16(v);
}

__global__ __launch_bounds__(256) void f32_to_bf16_kernel(
    const float* __restrict__ in, ushort* __restrict__ out, int n4) {
  int i = blockIdx.x * blockDim.x + threadIdx.x;
  if (i >= n4) return;
  const float4 v = ((const float4*)in)[i];
  ushort4 o;
  o.x = f2bf(v.x); o.y = f2bf(v.y); o.z = f2bf(v.z); o.w = f2bf(v.w);
  ((ushort4*)out)[i] = o;
}

// C[M,N] = A[M,K](bf16) * B[N,K]^T(bf16), fp32 acc. m97 structure: 128x128
// block tile, BK=32, both operands staged via global_load_lds width 16,
// ds_read_b128 fragments. Block 256 = 4 waves, wave tile 64x64.
template <typename OUT_T>
__global__ __launch_bounds__(256) void gemm_kernel(
    const ushort* __restrict__ A, int lda, const ushort* __restrict__ B, int ldb,
    OUT_T* __restrict__ C, int ldc, int K) {
  __shared__ __align__(16) ushort As[128 * 32];
  __shared__ __align__(16) ushort Bs[128 * 32];
  const int tid = threadIdx.x;
  const int wave = tid >> 6, lane = tid & 63;
  const int lm = lane & 15, quad = lane >> 4;
  const size_t m0 = (size_t)blockIdx.y * 128;
  const size_t n0 = (size_t)blockIdx.x * 128;
  const int srow = lane >> 2;       // 4 lanes/row * 8 ushort
  const int scol = (lane & 3) * 8;

  f32x4 acc[4][4] = {};
  for (int k0 = 0; k0 < K; k0 += 32) {
    __syncthreads();
#pragma unroll
    for (int j = 0; j < 2; ++j) {
      const int ch = wave * 2 + j;  // 16-row chunk
      const ushort* gb = B + (n0 + ch * 16 + srow) * (size_t)ldb + k0 + scol;
      __builtin_amdgcn_global_load_lds(
          (const __attribute__((address_space(1))) void*)gb,
          (__attribute__((address_space(3))) void*)(Bs + ch * 512), 16, 0, 0);
      const ushort* ga = A + (m0 + ch * 16 + srow) * (size_t)lda + k0 + scol;
      __builtin_amdgcn_global_load_lds(
          (const __attribute__((address_space(1))) void*)ga,
          (__attribute__((address_space(3))) void*)(As + ch * 512), 16, 0, 0);
    }
    __syncthreads();

    const int wm = (wave >> 1) * 64, wn = (wave & 1) * 64;
    short8 a[4], b[4];
#pragma unroll
    for (int i = 0; i < 4; ++i)
      a[i] = *(const short8*)(As + (wm + i * 16 + lm) * 32 + quad * 8);
#pragma unroll
    for (int j = 0; j < 4; ++j)
      b[j] = *(const short8*)(Bs + (wn + j * 16 + lm) * 32 + quad * 8);
#pragma unroll
    for (int i = 0; i < 4; ++i)
#pragma unroll
      for (int j = 0; j < 4; ++j)
        acc[i][j] = MFMA16(a[i], b[j], acc[i][j]);
  }

  const int wm = (wave >> 1) * 64, wn = (wave & 1) * 64;
  const int rq = quad * 4;
#pragma unroll
  for (int i = 0; i < 4; ++i)
#pragma unroll
    for (int j = 0; j < 4; ++j)
#pragma unroll
      for (int r = 0; r < 4; ++r)
        store_out(&C[(m0 + wm + i * 16 + rq + r) * (size_t)ldc + n0 + wn + j * 16 + lm],
                  acc[i][j][r]);
}

// Swizzled V^T LDS write: 8 cols starting at h0 for row p.
// Element (p, h) lives at h*64 + (((p>>3) ^ (h>>3) ^ (h&7)) & 7)*8 + (p&7).
static __device__ __forceinline__ void vt_write8(ushort* vtbuf, int h0, int hsw,
                                                 int p, const short8& v) {
  const int pc = (p >> 3) ^ hsw;
  ushort* row = vtbuf + h0 * 64 + (p & 7);
#pragma unroll
  for (int u = 0; u < 8; ++u)
    row[u * 64 + (((pc ^ u) & 7) << 3)] = ((const ushort*)&v)[u];
}

// Stage a 64x64 bf16 K tile (global rows pbase..pbase+63) into kbuf via
// global_load_lds. LDS dest is linear (wave-uniform base + lane*16); the
// chunk swizzle is applied on the per-lane GLOBAL source address (rule 21).
// Element (r, c) [c = 8-ushort chunk 0..7] lands at kbuf + r*64 + (c^(r&7))*8.
// Wave w covers chunks w*2, w*2+1 (8 rows each).
static __device__ __forceinline__ void stage_k(const ushort* kglob, int pbase,
                                               ushort* kbuf, int wave, int lane) {
  const int rl = lane >> 3;           // row within the 8-row chunk (== r&7)
  const int c = (lane & 7) ^ rl;      // inverse-swizzled source chunk
#pragma unroll
  for (int j = 0; j < 2; ++j) {
    const int ch = wave * 2 + j;
    const ushort* src = kglob + (size_t)(pbase + ch * 8 + rl) * 3072 + c * 8;
    __builtin_amdgcn_global_load_lds(
        (const __attribute__((address_space(1))) void*)src,
        (__attribute__((address_space(3))) void*)(kbuf + ch * 512), 16, 0, 0);
  }
}

// Flash causal attention. QKV[8192][3072]: Q cols 0..1023, K 1024..2047,
// V 2048..3071; head h at sub-col h*64; row = b*2048 + pos. Z over Q in-place.
// Flat grid 1024, XCD-remapped: id&7 = xcd slot; all 16 q-pair blocks of one
// (b,head) group land on one XCD (8 groups/XCD) so K/V stay L2-resident.
// Each block runs q-tile pair (m, 31-m) -> exactly 33 p-tile iters.
// Block = 4 waves; wave = 16 q-rows. S^T = K*Q^T: lane owns q-row qrow+lm.
// Fixed-shift softmax: p = exp2(S*log2e/8) (exact; scores bounded ~10).
// K: block-shared LDS, double-buffered, staged by global_load_lds with
// pre-swizzled source; fragment ds_reads 2-way max (free).
// V^T: double-buffered LDS (xor-swizzled both sides). P: per-wave LDS.
__global__ __launch_bounds__(256) void flash4_kernel(ushort* __restrict__ QKV) {
  constexpr int LD = 3072;
  __shared__ __align__(16) ushort vt[2][64 * 64];
  __shared__ __align__(16) ushort kt[2][64 * 64];
  __shared__ __align__(16) ushort pbuf[4][16 * 64];

  const int id = blockIdx.x;
  const int g = (id & 7) * 8 + ((id >> 3) & 7);  // (b,head) group, XCD-local
  const int m = id >> 6;                          // q-pair index 0..15
  const int head = g & 15;
  const int b = g >> 4;

  const int tid = threadIdx.x;
  const int wave = tid >> 6, lane = tid & 63;
  const int lm = lane & 15, quad = lane >> 4;

  const size_t qcol = (size_t)b * 2048 * LD + head * 64;
  const size_t vcol = qcol + 2048;
  const ushort* kglob = QKV + qcol + 1024;

  const int h0 = (tid & 7) * 8;  // V staging: 8 cols per thread
  const int hsw = tid & 7;
  const int plb = tid >> 3;      // V staging p base (0..31)
  const int psw = lm & 7;        // pbuf row swizzle key
  const int ksw = lm & 7;        // kt fragment swizzle key

  constexpr float CSC = 0.180336880f;  // log2(e)/8

  for (int pass = 0; pass < 2; ++pass) {
    const int qbi = pass ? 31 - m : m;
    const int qrow = qbi * 64 + wave * 16;
    const int qg = qrow + lm;
    const int nt = qbi + 1;

    const ushort* qp = QKV + qcol + (size_t)(qrow + lm) * LD;
    short8 qa0 = *(const short8*)(qp + quad * 8);
    short8 qa1 = *(const short8*)(qp + 32 + quad * 8);

    f32x4 accz[4] = {};   // Z C-layout: row q=quad*4+r, col h=c*16+lm
    float l_l = 0.f;      // per-lane partial row-sum for row qg

    block_sync_lds();  // prior pass's vt/kt reads complete before restage

    // K tile 0 -> kt[0] (direct-to-LDS), V tile 0 -> vt[0] (reg-staged)
    stage_k(kglob, 0, kt[0], wave, lane);
#pragma unroll
    for (int rr = 0; rr < 2; ++rr) {
      const int p = plb + rr * 32;
      short8 v = *(const short8*)(QKV + vcol + (size_t)p * LD + h0);
      vt_write8(vt[0], h0, hsw, p, v);
    }

    for (int it = 0; it < nt; ++it) {
      const int p0 = it * 64;
      // kt/vt of this iter visible. Only the 2 stage_k loads (issued a full
      // iter ago) are drained by vmcnt(0).
      block_sync_full();

      // K fragments from LDS (block-shared; swizzled chunks, 2-way max)
      short8 ka[4], kb[4];
      const ushort* kbuf = kt[it & 1];
#pragma unroll
      for (int s = 0; s < 4; ++s) {
        const ushort* kr = kbuf + (s * 16 + lm) * 64;
        ka[s] = *(const short8*)(kr + (((quad ^ ksw) & 7) << 3));
        kb[s] = *(const short8*)(kr + ((((quad + 4) ^ ksw) & 7) << 3));
      }

      const bool more = (it + 1 < nt);
      // early global V load for it+1 (LDS write deferred to end of iter)
      short8 nv0, nv1;
      if (more) {
        nv0 = *(const short8*)(QKV + vcol + (size_t)(p0 + 64 + plb) * LD + h0);
        nv1 = *(const short8*)(QKV + vcol + (size_t)(p0 + 96 + plb) * LD + h0);
        // stage K for it+1 into the other buffer (issued AFTER nv: the nv
        // wait at vt_write8 is then vmcnt(2), leaving these in flight)
        stage_k(kglob, p0 + 64, kt[(it + 1) & 1], wave, lane);
      }

      // scores S^T[p][q] (8 MFMA)
      f32x4 t4[4];
#pragma unroll
      for (int s = 0; s < 4; ++s) {
        f32x4 t = {0.f, 0.f, 0.f, 0.f};
        t = MFMA16(ka[s], qa0, t);
        t = MFMA16(kb[s], qa1, t);
        t4[s] = t;
      }

      // fixed-shift softmax: p = exp2(S*log2e/8); mask only on diagonal tile
      float ps[4][4];
      if (it != nt - 1) {
#pragma unroll
        for (int s = 0; s < 4; ++s) {
#pragma unroll
          for (int r = 0; r < 4; ++r)
            ps[s][r] = fexp2(t4[s][r] * CSC);
          l_l += (ps[s][0] + ps[s][1]) + (ps[s][2] + ps[s][3]);
        }
      } else {
#pragma unroll
        for (int s = 0; s < 4; ++s) {
#pragma unroll
          for (int r = 0; r < 4; ++r) {
            const int pg = p0 + s * 16 + quad * 4 + r;
            const float e = fexp2(t4[s][r] * CSC);
            ps[s][r] = (pg > qg) ? 0.f : e;
          }
          l_l += (ps[s][0] + ps[s][1]) + (ps[s][2] + ps[s][3]);
        }
      }

      // pack P^T (C-layout) -> per-wave LDS (same-wave, no barrier).
      ushort* pw = pbuf[wave] + lm * 64;
#pragma unroll
      for (int s = 0; s < 4; ++s) {
        uint2 pk;
        pk.x = (uint)f2bf(ps[s][0]) | ((uint)f2bf(ps[s][1]) << 16);
        pk.y = (uint)f2bf(ps[s][2]) | ((uint)f2bf(ps[s][3]) << 16);
        *(uint2*)(pw + ((((2 * s + (quad >> 1)) ^ psw) & 7) << 3) +
                  ((quad & 1) << 2)) = pk;
      }

      // PV: accz[q][h] += P[q][p] * V[p][h]
      const ushort* vbuf = vt[it & 1];
#pragma unroll
      for (int kc = 0; kc < 2; ++kc) {
        short8 pa = *(const short8*)(pw + ((((kc * 4 + quad) ^ psw) & 7) << 3));
#pragma unroll
        for (int c = 0; c < 4; ++c) {
          const int hrow = c * 16 + lm;
          const int fh = ((hrow >> 3) ^ hrow) & 7;
          short8 vb = *(const short8*)(
              vbuf + hrow * 64 + ((((4 * kc + quad) ^ fh) & 7) << 3));
          accz[c] = MFMA16(pa, vb, accz[c]);
        }
      }

      // late LDS writes of next V tile; compiler waits vmcnt(2) for nv0/nv1
      // (stage_k loads stay outstanding until next barrier)
      if (more) {
        ushort* nbuf = vt[(it + 1) & 1];
        vt_write8(nbuf, h0, hsw, plb, nv0);
        vt_write8(nbuf, h0, hsw, plb + 32, nv1);
      }
    }

    // epilogue: full row-sums via 2 shfl_xor, then scale + write Z over Q
    float lt = l_l;
    lt += __shfl_xor(lt, 16, 64);
    lt += __shfl_xor(lt, 32, 64);
#pragma unroll
    for (int r = 0; r < 4; ++r) {
      const float lr = __shfl(lt, quad * 4 + r, 64);
      const float inv = 1.f / lr;
#pragma unroll
      for (int c = 0; c < 4; ++c)
        QKV[qcol + (size_t)(qrow + quad * 4 + r) * LD + c * 16 + lm] =
            f2bf(accz[c][r] * inv);
    }
  }
}

extern "C" void kernel_launch(void* const* d_in, const int* in_sizes, int n_in,
                              void* d_out, int out_size, void* d_ws, size_t ws_size,
                              hipStream_t stream) {
  (void)in_sizes; (void)n_in; (void)out_size; (void)ws_size;
  const float* x  = (const float*)d_in[0];   // (4,2048,1024) = (8192,1024)
  const float* wk = (const float*)d_in[1];   // (16,64,1024) flat (1024,1024)
  const float* wq = (const float*)d_in[2];
  const float* wv = (const float*)d_in[3];
  const float* wo = (const float*)d_in[4];   // (1024,1024)
  float* out = (float*)d_out;

  const size_t WSZ = (size_t)1024 * 1024;
  ushort* wqkv_b = (ushort*)d_ws;            // rows: 0..1023 Q, 1024.. K, 2048.. V
  ushort* wo_b = wqkv_b + 3 * WSZ;
  ushort* QKV = wo_b + WSZ;                  // 8192 x 3072
  ushort* xb = (ushort*)d_out;               // bf16 x in d_out (16 of 32 MB);
                                             // dead before out-proj writes

  const int wn4 = (int)(WSZ / 4);
  const int xn4 = (int)((size_t)8192 * 1024 / 4);
  f32_to_bf16_kernel<<<(wn4 + 255) / 256, 256, 0, stream>>>(wq, wqkv_b, wn4);
  f32_to_bf16_kernel<<<(wn4 + 255) / 256, 256, 0, stream>>>(wk, wqkv_b + WSZ, wn4);
  f32_to_bf16_kernel<<<(wn4 + 255) / 256, 256, 0, stream>>>(wv, wqkv_b + 2 * WSZ, wn4);
  f32_to_bf16_kernel<<<(wn4 + 255) / 256, 256, 0, stream>>>(wo, wo_b, wn4);
  f32_to_bf16_kernel<<<(xn4 + 255) / 256, 256, 0, stream>>>(x, xb, xn4);

  // All-batch QKV projection (pure bf16, global_load_lds staging).
  gemm_kernel<__hip_bfloat16><<<dim3(24, 64), 256, 0, stream>>>(
      xb, 1024, wqkv_b, 1024, (__hip_bfloat16*)QKV, 3072, 1024);

  flash4_kernel<<<1024, 256, 0, stream>>>(QKV);

  // Out projection: Z (QKV cols 0..1023) * Wo^T -> fp32 out.
  gemm_kernel<float><<<dim3(8, 64), 256, 0, stream>>>(
      QKV, 3072, wo_b, 1024, out, 1024, 1024);
}

// Round 4
// 262.328 us; speedup vs baseline: 1.3669x; 1.0704x over previous
//
#include <hip/hip_runtime.h>
#include <hip/hip_bf16.h>

// Attention forward, MI355X (gfx950). fp32 in/out, bf16 MFMA internally.
// ws (56 MB): wqkv_b[3072x1024 bf16] | wo_b[1024x1024 bf16] | QKV[8192x3072 bf16]
// xb (bf16 x) lives in d_out's first 16 MB (dead before out-proj writes).
// Dispatches: 1 fused convert; QKV GEMM; flash; out-proj GEMM.
// MFMA layouts (verified m89/m74):
//   A-frag: A[m=lane&15][k=(lane>>4)*8+j]; B-frag: B[n=lane&15][k=...]
//   C/D:    col=lane&15, row=(lane>>4)*4+reg
//
// Round-8:  both-sides LDS swizzles in flash. Conflicts 1.62e7->6.5e6, dur flat.
// Round-9:  lgkm-only barrier in flash. 163->157 us.
// Round-10: K LDS-staged (pre-swizzled source) + XCD grouping in flash.
//           FETCH 240->38 MB, flash 157->89.6 us. Latency theory confirmed.
// Round-11 (this): GEMM side (~190 us total incl converts/gaps):
//   (a) XCD N-chunk ownership remap for both GEMMs (id&7=XCD owns cpx
//       N-tiles; B sub-panel L2-resident, A row-panel shared by consecutive
//       local ids). Same remap class that fixed flash.
//   (b) BK=64 with flash-validated stage swizzle: half the barriers per
//       K-loop, conflict-free ds_read_b128 fragments. LDS 32 KB.
//   (c) 5 converts fused into 1 kernel (fewer launch gaps).
//   Flash kernel untouched.

typedef short short8 __attribute__((ext_vector_type(8)));
typedef float f32x4 __attribute__((ext_vector_type(4)));

#define MFMA16(a, b, c) __builtin_amdgcn_mfma_f32_16x16x32_bf16((a), (b), (c), 0, 0, 0)

static __device__ __forceinline__ ushort f2bf(float f) {
  union { __hip_bfloat16 h; ushort u; } cv;
  cv.h = __float2bfloat16(f);
  return cv.u;
}

static __device__ __forceinline__ float fexp2(float x) {
#if __has_builtin(__builtin_amdgcn_exp2f)
  return __builtin_amdgcn_exp2f(x);
#else
  return __expf(x * 0.69314718056f);
#endif
}

// Barrier WITHOUT any vmcnt drain: LDS writes visible, globals keep flying.
static __device__ __forceinline__ void block_sync_lds() {
  asm volatile("s_waitcnt lgkmcnt(0)" ::: "memory");
  __builtin_amdgcn_s_barrier();
  __builtin_amdgcn_sched_barrier(0);
}

// Barrier that ALSO waits outstanding globals (global_load_lds visibility).
static __device__ __forceinline__ void block_sync_full() {
  asm volatile("s_waitcnt vmcnt(0) lgkmcnt(0)" ::: "memory");
  __builtin_amdgcn_s_barrier();
  __builtin_amdgcn_sched_barrier(0);
}

static __device__ __forceinline__ void store_out(float* p, float v) { *p = v; }
static __device__ __forceinline__ void store_out(__hip_bfloat16* p, float v) {
  *p = __float2bfloat16(v);
}

// One fused convert: wq|wk|wv -> wqkv_b rows, wo -> wo_b, x -> xb.
// Region-dispatched flat float4 index; grid covers exactly 3145728 float4s.
__global__ __launch_bounds__(256) void convert_all_kernel(
    const float* __restrict__ wq, const float* __restrict__ wk,
    const float* __restrict__ wv, const float* __restrict__ wo,
    const float* __restrict__ x, ushort* __restrict__ wqkv,
    ushort* __restrict__ wob, ushort* __restrict__ xb) {
  constexpr int W4 = 262144;           // (1024*1024)/4
  constexpr size_t WSZ = (size_t)1024 * 1024;
  const int i = blockIdx.x * blockDim.x + threadIdx.x;
  const float* src;
  ushort* dst;
  int j;
  if (i < 2 * W4) {
    if (i < W4)      { src = wq; dst = wqkv;           j = i; }
    else             { src = wk; dst = wqkv + WSZ;     j = i - W4; }
  } else if (i < 4 * W4) {
    if (i < 3 * W4)  { src = wv; dst = wqkv + 2 * WSZ; j = i - 2 * W4; }
    else             { src = wo; dst = wob;            j = i - 3 * W4; }
  } else {
    src = x; dst = xb; j = i - 4 * W4;
  }
  const float4 v = ((const float4*)src)[j];
  ushort4 o;
  o.x = f2bf(v.x); o.y = f2bf(v.y); o.z = f2bf(v.z); o.w = f2bf(v.w);
  ((ushort4*)dst)[j] = o;
}

// C[M,N] = A[M,K](bf16) * B[N,K]^T(bf16), fp32 acc. 128x128 block tile,
// BK=64, both operands staged via global_load_lds width 16 with PRE-SWIZZLED
// SOURCE (rule 21; flash-validated): LDS element (r, phys-chunk pc) holds
// global col-chunk pc^(r&7), so fragment reads at phys (c^(lm&7)) are
// conflict-free (2 lanes/bank). Block 256 = 4 waves, wave tile 64x64.
// XCD remap: id&7 = XCD (HW round-robin); XCD x owns N-tiles
// x*cpx..x*cpx+cpx-1; consecutive local ids share one A row-panel.
template <typename OUT_T>
__global__ __launch_bounds__(256) void gemm_kernel(
    const ushort* __restrict__ A, int lda, const ushort* __restrict__ B, int ldb,
    OUT_T* __restrict__ C, int ldc, int K, int cpx) {
  __shared__ __align__(16) ushort As[128 * 64];
  __shared__ __align__(16) ushort Bs[128 * 64];
  const int tid = threadIdx.x;
  const int wave = tid >> 6, lane = tid & 63;
  const int lm = lane & 15, quad = lane >> 4;

  const int id = blockIdx.x;
  const int local = id >> 3;
  const int nt = (id & 7) * cpx + local % cpx;
  const int mt = local / cpx;
  const size_t m0 = (size_t)mt * 128;
  const size_t n0 = (size_t)nt * 128;

  const int rl = lane >> 3;        // row within 8-row staging chunk
  const int cs = (lane & 7) ^ rl;  // pre-swizzled source col-chunk
  const int fsw = lm & 7;          // fragment read swizzle key

  f32x4 acc[4][4] = {};
  for (int k0 = 0; k0 < K; k0 += 64) {
    __syncthreads();
#pragma unroll
    for (int j = 0; j < 4; ++j) {
      const int ch = wave * 4 + j;  // 8-row chunk 0..15
      const ushort* gb = B + (n0 + ch * 8 + rl) * (size_t)ldb + k0 + cs * 8;
      __builtin_amdgcn_global_load_lds(
          (const __attribute__((address_space(1))) void*)gb,
          (__attribute__((address_space(3))) void*)(Bs + ch * 512), 16, 0, 0);
      const ushort* ga = A + (m0 + ch * 8 + rl) * (size_t)lda + k0 + cs * 8;
      __builtin_amdgcn_global_load_lds(
          (const __attribute__((address_space(1))) void*)ga,
          (__attribute__((address_space(3))) void*)(As + ch * 512), 16, 0, 0);
    }
    __syncthreads();  // vmcnt drain required: staging must be visible

    const int wm = (wave >> 1) * 64, wn = (wave & 1) * 64;
#pragma unroll
    for (int ks = 0; ks < 2; ++ks) {
      short8 a[4], b[4];
#pragma unroll
      for (int i = 0; i < 4; ++i)
        a[i] = *(const short8*)(As + (wm + i * 16 + lm) * 64 +
                                ((((ks * 4 + quad) ^ fsw) & 7) << 3));
#pragma unroll
      for (int j = 0; j < 4; ++j)
        b[j] = *(const short8*)(Bs + (wn + j * 16 + lm) * 64 +
                                ((((ks * 4 + quad) ^ fsw) & 7) << 3));
#pragma unroll
      for (int i = 0; i < 4; ++i)
#pragma unroll
        for (int j = 0; j < 4; ++j)
          acc[i][j] = MFMA16(a[i], b[j], acc[i][j]);
    }
  }

  const int wm = (wave >> 1) * 64, wn = (wave & 1) * 64;
  const int rq = quad * 4;
#pragma unroll
  for (int i = 0; i < 4; ++i)
#pragma unroll
    for (int j = 0; j < 4; ++j)
#pragma unroll
      for (int r = 0; r < 4; ++r)
        store_out(&C[(m0 + wm + i * 16 + rq + r) * (size_t)ldc + n0 + wn + j * 16 + lm],
                  acc[i][j][r]);
}

// Swizzled V^T LDS write: 8 cols starting at h0 for row p.
// Element (p, h) lives at h*64 + (((p>>3) ^ (h>>3) ^ (h&7)) & 7)*8 + (p&7).
static __device__ __forceinline__ void vt_write8(ushort* vtbuf, int h0, int hsw,
                                                 int p, const short8& v) {
  const int pc = (p >> 3) ^ hsw;
  ushort* row = vtbuf + h0 * 64 + (p & 7);
#pragma unroll
  for (int u = 0; u < 8; ++u)
    row[u * 64 + (((pc ^ u) & 7) << 3)] = ((const ushort*)&v)[u];
}

// Stage a 64x64 bf16 K tile (global rows pbase..pbase+63) into kbuf via
// global_load_lds, pre-swizzled source (rule 21).
static __device__ __forceinline__ void stage_k(const ushort* kglob, int pbase,
                                               ushort* kbuf, int wave, int lane) {
  const int rl = lane >> 3;           // row within the 8-row chunk (== r&7)
  const int c = (lane & 7) ^ rl;      // inverse-swizzled source chunk
#pragma unroll
  for (int j = 0; j < 2; ++j) {
    const int ch = wave * 2 + j;
    const ushort* src = kglob + (size_t)(pbase + ch * 8 + rl) * 3072 + c * 8;
    __builtin_amdgcn_global_load_lds(
        (const __attribute__((address_space(1))) void*)src,
        (__attribute__((address_space(3))) void*)(kbuf + ch * 512), 16, 0, 0);
  }
}

// Flash causal attention. QKV[8192][3072]: Q cols 0..1023, K 1024..2047,
// V 2048..3071; head h at sub-col h*64; row = b*2048 + pos. Z over Q in-place.
// Flat grid 1024, XCD-remapped: id&7 = xcd slot; all 16 q-pair blocks of one
// (b,head) group land on one XCD (8 groups/XCD) so K/V stay L2-resident.
// Each block runs q-tile pair (m, 31-m) -> exactly 33 p-tile iters.
// Block = 4 waves; wave = 16 q-rows. S^T = K*Q^T: lane owns q-row qrow+lm.
// Fixed-shift softmax: p = exp2(S*log2e/8) (exact; scores bounded ~10).
// K: block-shared LDS, double-buffered, staged by global_load_lds with
// pre-swizzled source; fragment ds_reads 2-way max (free).
// V^T: double-buffered LDS (xor-swizzled both sides). P: per-wave LDS.
__global__ __launch_bounds__(256) void flash4_kernel(ushort* __restrict__ QKV) {
  constexpr int LD = 3072;
  __shared__ __align__(16) ushort vt[2][64 * 64];
  __shared__ __align__(16) ushort kt[2][64 * 64];
  __shared__ __align__(16) ushort pbuf[4][16 * 64];

  const int id = blockIdx.x;
  const int g = (id & 7) * 8 + ((id >> 3) & 7);  // (b,head) group, XCD-local
  const int m = id >> 6;                          // q-pair index 0..15
  const int head = g & 15;
  const int b = g >> 4;

  const int tid = threadIdx.x;
  const int wave = tid >> 6, lane = tid & 63;
  const int lm = lane & 15, quad = lane >> 4;

  const size_t qcol = (size_t)b * 2048 * LD + head * 64;
  const size_t vcol = qcol + 2048;
  const ushort* kglob = QKV + qcol + 1024;

  const int h0 = (tid & 7) * 8;  // V staging: 8 cols per thread
  const int hsw = tid & 7;
  const int plb = tid >> 3;      // V staging p base (0..31)
  const int psw = lm & 7;        // pbuf row swizzle key
  const int ksw = lm & 7;        // kt fragment swizzle key

  constexpr float CSC = 0.180336880f;  // log2(e)/8

  for (int pass = 0; pass < 2; ++pass) {
    const int qbi = pass ? 31 - m : m;
    const int qrow = qbi * 64 + wave * 16;
    const int qg = qrow + lm;
    const int nt = qbi + 1;

    const ushort* qp = QKV + qcol + (size_t)(qrow + lm) * LD;
    short8 qa0 = *(const short8*)(qp + quad * 8);
    short8 qa1 = *(const short8*)(qp + 32 + quad * 8);

    f32x4 accz[4] = {};   // Z C-layout: row q=quad*4+r, col h=c*16+lm
    float l_l = 0.f;      // per-lane partial row-sum for row qg

    block_sync_lds();  // prior pass's vt/kt reads complete before restage

    // K tile 0 -> kt[0] (direct-to-LDS), V tile 0 -> vt[0] (reg-staged)
    stage_k(kglob, 0, kt[0], wave, lane);
#pragma unroll
    for (int rr = 0; rr < 2; ++rr) {
      const int p = plb + rr * 32;
      short8 v = *(const short8*)(QKV + vcol + (size_t)p * LD + h0);
      vt_write8(vt[0], h0, hsw, p, v);
    }

    for (int it = 0; it < nt; ++it) {
      const int p0 = it * 64;
      // kt/vt of this iter visible. Only the 2 stage_k loads (issued a full
      // iter ago) are drained by vmcnt(0).
      block_sync_full();

      // K fragments from LDS (block-shared; swizzled chunks, 2-way max)
      short8 ka[4], kb[4];
      const ushort* kbuf = kt[it & 1];
#pragma unroll
      for (int s = 0; s < 4; ++s) {
        const ushort* kr = kbuf + (s * 16 + lm) * 64;
        ka[s] = *(const short8*)(kr + (((quad ^ ksw) & 7) << 3));
        kb[s] = *(const short8*)(kr + ((((quad + 4) ^ ksw) & 7) << 3));
      }

      const bool more = (it + 1 < nt);
      // early global V load for it+1 (LDS write deferred to end of iter)
      short8 nv0, nv1;
      if (more) {
        nv0 = *(const short8*)(QKV + vcol + (size_t)(p0 + 64 + plb) * LD + h0);
        nv1 = *(const short8*)(QKV + vcol + (size_t)(p0 + 96 + plb) * LD + h0);
        // stage K for it+1 into the other buffer (issued AFTER nv: the nv
        // wait at vt_write8 is then vmcnt(2), leaving these in flight)
        stage_k(kglob, p0 + 64, kt[(it + 1) & 1], wave, lane);
      }

      // scores S^T[p][q] (8 MFMA)
      f32x4 t4[4];
#pragma unroll
      for (int s = 0; s < 4; ++s) {
        f32x4 t = {0.f, 0.f, 0.f, 0.f};
        t = MFMA16(ka[s], qa0, t);
        t = MFMA16(kb[s], qa1, t);
        t4[s] = t;
      }

      // fixed-shift softmax: p = exp2(S*log2e/8); mask only on diagonal tile
      float ps[4][4];
      if (it != nt - 1) {
#pragma unroll
        for (int s = 0; s < 4; ++s) {
#pragma unroll
          for (int r = 0; r < 4; ++r)
            ps[s][r] = fexp2(t4[s][r] * CSC);
          l_l += (ps[s][0] + ps[s][1]) + (ps[s][2] + ps[s][3]);
        }
      } else {
#pragma unroll
        for (int s = 0; s < 4; ++s) {
#pragma unroll
          for (int r = 0; r < 4; ++r) {
            const int pg = p0 + s * 16 + quad * 4 + r;
            const float e = fexp2(t4[s][r] * CSC);
            ps[s][r] = (pg > qg) ? 0.f : e;
          }
          l_l += (ps[s][0] + ps[s][1]) + (ps[s][2] + ps[s][3]);
        }
      }

      // pack P^T (C-layout) -> per-wave LDS (same-wave, no barrier).
      ushort* pw = pbuf[wave] + lm * 64;
#pragma unroll
      for (int s = 0; s < 4; ++s) {
        uint2 pk;
        pk.x = (uint)f2bf(ps[s][0]) | ((uint)f2bf(ps[s][1]) << 16);
        pk.y = (uint)f2bf(ps[s][2]) | ((uint)f2bf(ps[s][3]) << 16);
        *(uint2*)(pw + ((((2 * s + (quad >> 1)) ^ psw) & 7) << 3) +
                  ((quad & 1) << 2)) = pk;
      }

      // PV: accz[q][h] += P[q][p] * V[p][h]
      const ushort* vbuf = vt[it & 1];
#pragma unroll
      for (int kc = 0; kc < 2; ++kc) {
        short8 pa = *(const short8*)(pw + ((((kc * 4 + quad) ^ psw) & 7) << 3));
#pragma unroll
        for (int c = 0; c < 4; ++c) {
          const int hrow = c * 16 + lm;
          const int fh = ((hrow >> 3) ^ hrow) & 7;
          short8 vb = *(const short8*)(
              vbuf + hrow * 64 + ((((4 * kc + quad) ^ fh) & 7) << 3));
          accz[c] = MFMA16(pa, vb, accz[c]);
        }
      }

      // late LDS writes of next V tile; compiler waits vmcnt(2) for nv0/nv1
      // (stage_k loads stay outstanding until next barrier)
      if (more) {
        ushort* nbuf = vt[(it + 1) & 1];
        vt_write8(nbuf, h0, hsw, plb, nv0);
        vt_write8(nbuf, h0, hsw, plb + 32, nv1);
      }
    }

    // epilogue: full row-sums via 2 shfl_xor, then scale + write Z over Q
    float lt = l_l;
    lt += __shfl_xor(lt, 16, 64);
    lt += __shfl_xor(lt, 32, 64);
#pragma unroll
    for (int r = 0; r < 4; ++r) {
      const float lr = __shfl(lt, quad * 4 + r, 64);
      const float inv = 1.f / lr;
#pragma unroll
      for (int c = 0; c < 4; ++c)
        QKV[qcol + (size_t)(qrow + quad * 4 + r) * LD + c * 16 + lm] =
            f2bf(accz[c][r] * inv);
    }
  }
}

extern "C" void kernel_launch(void* const* d_in, const int* in_sizes, int n_in,
                              void* d_out, int out_size, void* d_ws, size_t ws_size,
                              hipStream_t stream) {
  (void)in_sizes; (void)n_in; (void)out_size; (void)ws_size;
  const float* x  = (const float*)d_in[0];   // (4,2048,1024) = (8192,1024)
  const float* wk = (const float*)d_in[1];   // (16,64,1024) flat (1024,1024)
  const float* wq = (const float*)d_in[2];
  const float* wv = (const float*)d_in[3];
  const float* wo = (const float*)d_in[4];   // (1024,1024)
  float* out = (float*)d_out;

  const size_t WSZ = (size_t)1024 * 1024;
  ushort* wqkv_b = (ushort*)d_ws;            // rows: 0..1023 Q, 1024.. K, 2048.. V
  ushort* wo_b = wqkv_b + 3 * WSZ;
  ushort* QKV = wo_b + WSZ;                  // 8192 x 3072
  ushort* xb = (ushort*)d_out;               // bf16 x in d_out (16 of 32 MB);
                                             // dead before out-proj writes

  // Fused converts: 4*(1M/4) + (8M/4) = 3145728 float4s = 12288 blocks exact.
  convert_all_kernel<<<12288, 256, 0, stream>>>(wq, wk, wv, wo, x,
                                                wqkv_b, wo_b, xb);

  // All-batch QKV projection. Grid 24 N-tiles x 64 M-tiles = 1536 blocks;
  // XCD remap cpx=3 (24/8): each XCD's 768 KB B sub-panel stays L2-resident.
  gemm_kernel<__hip_bfloat16><<<1536, 256, 0, stream>>>(
      xb, 1024, wqkv_b, 1024, (__hip_bfloat16*)QKV, 3072, 1024, 3);

  flash4_kernel<<<1024, 256, 0, stream>>>(QKV);

  // Out projection: Z (QKV cols 0..1023) * Wo^T -> fp32 out.
  // Grid 8 N-tiles x 64 M-tiles = 512 blocks; cpx=1 (one N-tile per XCD).
  gemm_kernel<float><<<512, 256, 0, stream>>>(
      QKV, 3072, wo_b, 1024, out, 1024, 1024, 1);
}